// Round 5
// baseline (103.694 us; speedup 1.0000x reference)
//
#include <hip/hip_runtime.h>
#include <stddef.h>

// Additive attention: out = softmax_k(mask(sum_h wv_h * tanh(qW_h + kW_h))) @ V
// tanh(q+k) = 1 - 2/(1 + e^{2q} e^{2k})  -> precompute Eq=e^{2q}, Ek=e^{2k};
// score = W0 + sum_h wv2_h * rcp(1 + Eq_h*Ek_h), wv2 = -2*wv, W0 = sum_h wv_h.
// |score| <= W1 = sum_h |wv_h|  ->  softmax without a global max pass:
//   p = exp2((s - W1)*L2E) in [e^{-2W1}, 1]; normalize by the total sum at the end.
//
// Pipeline: projq, projk -> fused scores+exp+PV partials (k-tile) -> reduce.

__device__ __forceinline__ float fast_rcp(float x)  { return __builtin_amdgcn_rcpf(x); }
__device__ __forceinline__ float fast_exp2(float x) { return __builtin_amdgcn_exp2f(x); }

#define C2F 2.88539008177792681f   // 2*log2(e)
#define L2E 1.44269504088896340f   // log2(e)

// ---------------------------------------------------------------------------
// Projection: P = in[rows x 256] @ W[256 x 64], out = exp2(C2F * P)
// ---------------------------------------------------------------------------
template<bool TRANSPOSED>
__global__ __launch_bounds__(256)
void proj_kernel(const float* __restrict__ in, const float* __restrict__ W,
                 float* __restrict__ out, const int* __restrict__ vlens,
                 int rowsPerB)
{
  const int t  = threadIdx.x;
  const int b  = blockIdx.x & 15;
  const int rt = blockIdx.x >> 4;
  const int r0 = rt * 64;
  if constexpr (TRANSPOSED) {
    if (r0 >= vlens[b]) return;
  }

  __shared__ float4 Wlds[256 * 16];   // [d][h-quad]
  __shared__ float  klds[64 * 36];

  const float4* W4 = (const float4*)W;
  #pragma unroll
  for (int i = 0; i < 16; ++i) Wlds[t + 256 * i] = W4[t + 256 * i];

  const float* inb = in + ((size_t)b * rowsPerB + r0) * 256;
  const int j = t >> 4;
  const int g = t & 15;

  float acc[4][4];
  #pragma unroll
  for (int m = 0; m < 4; ++m)
    acc[m][0] = acc[m][1] = acc[m][2] = acc[m][3] = 0.f;

  for (int dc = 0; dc < 8; ++dc) {
    {
      const int row = t >> 2, cs = (t & 3) * 8;
      const float* s = inb + row * 256 + dc * 32 + cs;
      float4 a0 = *(const float4*)s;
      float4 a1 = *(const float4*)(s + 4);
      float* dst = &klds[row * 36 + cs];
      *(float4*)dst       = a0;
      *(float4*)(dst + 4) = a1;
    }
    __syncthreads();
    #pragma unroll
    for (int d = 0; d < 32; ++d) {
      float4 w4 = Wlds[(dc * 32 + d) * 16 + j];
      #pragma unroll
      for (int m = 0; m < 4; ++m) {
        float kv = klds[(g + 16 * m) * 36 + d];
        acc[m][0] = fmaf(kv, w4.x, acc[m][0]);
        acc[m][1] = fmaf(kv, w4.y, acc[m][1]);
        acc[m][2] = fmaf(kv, w4.z, acc[m][2]);
        acc[m][3] = fmaf(kv, w4.w, acc[m][3]);
      }
    }
    __syncthreads();
  }

  if constexpr (TRANSPOSED) {
    #pragma unroll
    for (int m = 0; m < 4; ++m) {
      int k = r0 + g + 16 * m;
      size_t base = ((size_t)(b * 16 + (k >> 7)) * 64) * 128 + (k & 127);
      #pragma unroll
      for (int i = 0; i < 4; ++i)
        out[base + (size_t)(4 * j + i) * 128] = fast_exp2(C2F * acc[m][i]);
    }
  } else {
    #pragma unroll
    for (int m = 0; m < 4; ++m) {
      int row = r0 + g + 16 * m;
      float4 o;
      o.x = fast_exp2(C2F * acc[m][0]);
      o.y = fast_exp2(C2F * acc[m][1]);
      o.z = fast_exp2(C2F * acc[m][2]);
      o.w = fast_exp2(C2F * acc[m][3]);
      *(float4*)&out[((size_t)b * rowsPerB + row) * 64 + 4 * j] = o;
    }
  }
}

// ---------------------------------------------------------------------------
// Fused scores + exp + PV partial. 512 thr = 8 waves; wave owns 2 q.
// XCD-grouped dispatch: blocks sharing (b,kt) are == mod 8 -> same XCD L2,
// so the 32KB Ek tile + 64KB V tile are fetched from HBM once per group.
// ---------------------------------------------------------------------------
__global__ __launch_bounds__(512, 8)
void scorepv_kernel(const float* __restrict__ Eq, const float* __restrict__ EkT,
                    const float* __restrict__ values, const int* __restrict__ vlens,
                    const float* __restrict__ wv,
                    float* __restrict__ partial, float* __restrict__ tsum)
{
  const int blk = blockIdx.x;
  const int g   = blk & 255;           // (b,kt) group; indices == g (mod 8)
  const int qq  = blk >> 8;            // 0..7
  const int b   = g >> 4;
  const int kt  = g & 15;
  const int vl  = vlens[b];
  if (kt * 128 >= vl) return;

  __shared__ float ek_lds[64 * 128];   // 32KB; reused as p_lds[128][20] after barrier
  __shared__ float eq_lds[16 * 64];    // 4KB
  __shared__ float wv2_lds[64];

  const int t = threadIdx.x;

  float w0 = 0.f, W1 = 0.f;
  {
    const float4* wv4 = (const float4*)wv;
    #pragma unroll
    for (int u = 0; u < 16; ++u) {
      float4 v = wv4[u];
      w0 += v.x + v.y + v.z + v.w;
      W1 += fabsf(v.x) + fabsf(v.y) + fabsf(v.z) + fabsf(v.w);
    }
  }

  {
    const float4* src = (const float4*)(EkT + ((size_t)(b * 16 + kt) * 64) * 128);
    float4* dst = (float4*)ek_lds;
    #pragma unroll
    for (int i = 0; i < 4; ++i) dst[t + 512 * i] = src[t + 512 * i];
    if (t < 256) {
      const float4* qsrc = (const float4*)(Eq + (size_t)(b * 128 + qq * 16) * 64);
      ((float4*)eq_lds)[t] = qsrc[t];
    }
    if (t < 64) wv2_lds[t] = -2.0f * wv[t];
  }
  __syncthreads();

  const int wave = t >> 6, lane = t & 63;
  const int q0l = wave * 2;            // wave's 2 q rows (exclusive)
  const int kp  = lane * 2;            // lane's k pair

  float s[2][2];
  s[0][0] = s[0][1] = s[1][0] = s[1][1] = w0;

  #pragma unroll 4
  for (int h = 0; h < 64; ++h) {
    float2 ek = *(const float2*)&ek_lds[h * 128 + kp];
    float wvh = wv2_lds[h];
    #pragma unroll
    for (int q = 0; q < 2; ++q) {
      float eq = eq_lds[(q0l + q) * 64 + h];
      // paired reciprocal: 1 rcp serves 2 elems; wvh folded into it
      float x0 = fmaf(eq, ek.x, 1.0f);
      float x1 = fmaf(eq, ek.y, 1.0f);
      float y  = wvh * fast_rcp(x0 * x1);
      s[q][0] = fmaf(x1, y, s[q][0]);
      s[q][1] = fmaf(x0, y, s[q][1]);
    }
  }

  // p = exp2((s - W1)*L2E) in (0,1]; masked -> 0 (select, garbage-safe)
  const int kbase = kt * 128 + kp;
  float p[2][2];
  #pragma unroll
  for (int q = 0; q < 2; ++q) {
    p[q][0] = (kbase     < vl) ? fast_exp2((s[q][0] - W1) * L2E) : 0.f;
    p[q][1] = (kbase + 1 < vl) ? fast_exp2((s[q][1] - W1) * L2E) : 0.f;
  }

  // per-tile row sums (wave owns its q rows exclusively)
  #pragma unroll
  for (int q = 0; q < 2; ++q) {
    float e = p[q][0] + p[q][1];
    #pragma unroll
    for (int msk = 1; msk < 64; msk <<= 1) e += __shfl_xor(e, msk, 64);
    if (lane == 0)
      tsum[(size_t)(b * 16 + kt) * 128 + qq * 16 + q0l + q] = e;
  }

  __syncthreads();                     // all ek reads complete before reuse
  float* p_lds = ek_lds;               // [128 k][20 pad] (16B-aligned rows)
  #pragma unroll
  for (int q = 0; q < 2; ++q) {
    p_lds[kp * 20 + q0l + q]       = p[q][0];
    p_lds[(kp + 1) * 20 + q0l + q] = p[q][1];
  }
  __syncthreads();

  // PV: thread (grp -> 4-q group, v); per k: 1 V dword (L2) + 1 float4 p
  // broadcast (wave-uniform) + 4 fma
  const int v   = t & 127;
  const int grp = t >> 7;              // 0..3, wave-uniform
  const int qh  = grp * 4;
  const int kloc = min(128, vl - kt * 128);
  const float* vb = values + ((size_t)(b * 2048 + kt * 128)) * 128 + v;
  float acc[4] = {0.f, 0.f, 0.f, 0.f};
  #pragma unroll 8
  for (int k = 0; k < kloc; ++k) {
    float vx = vb[(size_t)k * 128];
    float4 pa = *(const float4*)&p_lds[k * 20 + qh];
    acc[0] = fmaf(pa.x, vx, acc[0]); acc[1] = fmaf(pa.y, vx, acc[1]);
    acc[2] = fmaf(pa.z, vx, acc[2]); acc[3] = fmaf(pa.w, vx, acc[3]);
  }
  const int qg = qq * 16 + qh;
  #pragma unroll
  for (int i = 0; i < 4; ++i)
    partial[(((size_t)(b * 128 + qg + i)) * 16 + kt) * 128 + v] = acc[i];
}

// ---------------------------------------------------------------------------
// Reduce: out[b][q][v] = sum_kt partial / sum_kt tsum. Block = (b, 2-q), 256 thr.
// ---------------------------------------------------------------------------
__global__ __launch_bounds__(256)
void reduce_kernel(const float* __restrict__ partial, const float* __restrict__ tsum,
                   const int* __restrict__ vlens, float* __restrict__ out)
{
  const int blk = blockIdx.x;          // b*64 + qp
  const int b   = blk >> 6;
  const int q   = (blk & 63) * 2 + (threadIdx.x >> 7);
  const int v   = threadIdx.x & 127;
  const int ntk = (vlens[b] + 127) >> 7;

  float tot = 0.f;
  for (int i = 0; i < ntk; ++i)
    tot += tsum[(size_t)(b * 16 + i) * 128 + q];

  float acc = 0.f;
  const float* pp = partial + ((size_t)(b * 128 + q)) * 16 * 128 + v;
  for (int i = 0; i < ntk; ++i)
    acc += pp[(size_t)i * 128];

  out[((size_t)(b * 128 + q)) * 128 + v] = acc / tot;
}

// ---------------------------------------------------------------------------
// Fallback fused kernel (round-1, known-correct) for small ws_size.
// ---------------------------------------------------------------------------
__global__ __launch_bounds__(256)
void attn_kernel(const float* __restrict__ Eq, const float* __restrict__ EkT,
                 const float* __restrict__ values, const int* __restrict__ vlens,
                 const float* __restrict__ wv, float* __restrict__ out)
{
  const int t    = threadIdx.x;
  const int b    = blockIdx.x & 15;
  const int qt   = blockIdx.x >> 4;
  const int wave = t >> 6;
  const int lane = t & 63;

  __shared__ float4 sc4[512 * 4];
  __shared__ float  pvp[128 * 5];
  __shared__ float  linvs[4];

  const int vl = vlens[b];

  float eqv[64], wv2[64];
  float w0 = 0.f;
  {
    const float4* eq4 = (const float4*)(Eq + (size_t)(b * 128 + qt * 4 + wave) * 64);
    const float4* wv4 = (const float4*)wv;
    #pragma unroll
    for (int u = 0; u < 16; ++u) {
      float4 e = eq4[u], v = wv4[u];
      eqv[4*u+0] = e.x; eqv[4*u+1] = e.y; eqv[4*u+2] = e.z; eqv[4*u+3] = e.w;
      wv2[4*u+0] = -2.f * v.x; wv2[4*u+1] = -2.f * v.y;
      wv2[4*u+2] = -2.f * v.z; wv2[4*u+3] = -2.f * v.w;
      w0 += v.x + v.y + v.z + v.w;
    }
  }

  const int ktiles = (vl + 127) >> 7;
  const int kp = 2 * lane;
  for (int kt = 0; kt < ktiles; ++kt) {
    const float* tb = EkT + ((size_t)(b * 16 + kt) * 64) * 128 + kp;
    float s0 = w0, s1 = w0;
    #pragma unroll
    for (int h = 0; h < 64; ++h) {
      float2 ek = *(const float2*)(tb + (size_t)h * 128);
      float r0 = fast_rcp(fmaf(eqv[h], ek.x, 1.0f));
      float r1 = fast_rcp(fmaf(eqv[h], ek.y, 1.0f));
      s0 = fmaf(wv2[h], r0, s0);
      s1 = fmaf(wv2[h], r1, s1);
    }
    int k = kt * 128 + kp;
    if (k     >= vl) s0 = -1e9f;
    if (k + 1 >= vl) s1 = -1e9f;
    float* scf = (float*)sc4;
    *(float2*)(scf + (((k >> 2) * 4 + wave) * 4 + (k & 3))) = make_float2(s0, s1);
  }

  const int nq4 = (vl + 3) >> 2;
  float mx = -3e38f;
  for (int Q = lane; Q < nq4; Q += 64) {
    float4 f = sc4[Q * 4 + wave];
    mx = fmaxf(mx, fmaxf(fmaxf(f.x, f.y), fmaxf(f.z, f.w)));
  }
  #pragma unroll
  for (int msk = 1; msk < 64; msk <<= 1) mx = fmaxf(mx, __shfl_xor(mx, msk, 64));
  float lsum = 0.f;
  for (int Q = lane; Q < nq4; Q += 64) {
    float4 f = sc4[Q * 4 + wave];
    f.x = fast_exp2((f.x - mx) * L2E);
    f.y = fast_exp2((f.y - mx) * L2E);
    f.z = fast_exp2((f.z - mx) * L2E);
    f.w = fast_exp2((f.w - mx) * L2E);
    sc4[Q * 4 + wave] = f;
    lsum += f.x + f.y + f.z + f.w;
  }
  #pragma unroll
  for (int msk = 1; msk < 64; msk <<= 1) lsum += __shfl_xor(lsum, msk, 64);
  if (lane == 0) linvs[wave] = fast_rcp(lsum);
  __syncthreads();

  const int grp = t >> 7, v = t & 127;
  float acc[4] = {0.f, 0.f, 0.f, 0.f};
  const float* vb = values + (size_t)b * 2048 * 128 + v;
  for (int Q = grp; Q < nq4; Q += 2) {
    float4 p0 = sc4[Q * 4 + 0], p1 = sc4[Q * 4 + 1];
    float4 p2 = sc4[Q * 4 + 2], p3 = sc4[Q * 4 + 3];
    const float* vk = vb + (size_t)(Q * 4) * 128;
    float x;
    x = vk[0];
    acc[0]=fmaf(p0.x,x,acc[0]); acc[1]=fmaf(p1.x,x,acc[1]);
    acc[2]=fmaf(p2.x,x,acc[2]); acc[3]=fmaf(p3.x,x,acc[3]);
    x = vk[128];
    acc[0]=fmaf(p0.y,x,acc[0]); acc[1]=fmaf(p1.y,x,acc[1]);
    acc[2]=fmaf(p2.y,x,acc[2]); acc[3]=fmaf(p3.y,x,acc[3]);
    x = vk[256];
    acc[0]=fmaf(p0.z,x,acc[0]); acc[1]=fmaf(p1.z,x,acc[1]);
    acc[2]=fmaf(p2.z,x,acc[2]); acc[3]=fmaf(p3.z,x,acc[3]);
    x = vk[384];
    acc[0]=fmaf(p0.w,x,acc[0]); acc[1]=fmaf(p1.w,x,acc[1]);
    acc[2]=fmaf(p2.w,x,acc[2]); acc[3]=fmaf(p3.w,x,acc[3]);
  }
  if (grp == 1) {
    #pragma unroll
    for (int qq = 0; qq < 4; ++qq) pvp[v * 5 + qq] = acc[qq];
  }
  __syncthreads();
  if (grp == 0) {
    #pragma unroll
    for (int qq = 0; qq < 4; ++qq) {
      float tot = acc[qq] + pvp[v * 5 + qq];
      out[((size_t)(b * 128) + qt * 4 + qq) * 128 + v] = tot * linvs[qq];
    }
  }
}

// ---------------------------------------------------------------------------
extern "C" void kernel_launch(void* const* d_in, const int* in_sizes, int n_in,
                              void* d_out, int out_size, void* d_ws, size_t ws_size,
                              hipStream_t stream) {
  const float* queries = (const float*)d_in[0];   // [16][128][256]
  const float* keys    = (const float*)d_in[1];   // [16][2048][256]
  const float* values  = (const float*)d_in[2];   // [16][2048][128]
  const int*   vlens   = (const int*)d_in[3];     // [16]
  const float* Wq      = (const float*)d_in[4];   // [256][64]
  const float* Wk      = (const float*)d_in[5];   // [256][64]
  const float* wv      = (const float*)d_in[6];   // [64]
  float* outp = (float*)d_out;

  float* base    = (float*)d_ws;
  float* Eq      = base;                 // 131072 f
  float* EkT     = base + 131072;        // 2097152 f
  float* tsumb   = base + 2228224;       // 32768 f   [b][kt][q]
  float* partial = base + 2260992;       // 4194304 f [b][q][kt][v]
  const size_t need = (size_t)(2260992 + 4194304) * 4;

  hipLaunchKernelGGL((proj_kernel<false>), dim3(32),  dim3(256), 0, stream,
                     queries, Wq, Eq, (const int*)nullptr, 128);
  hipLaunchKernelGGL((proj_kernel<true>),  dim3(512), dim3(256), 0, stream,
                     keys, Wk, EkT, vlens, 2048);

  if (ws_size >= need) {
    hipLaunchKernelGGL(scorepv_kernel, dim3(2048), dim3(512), 0, stream,
                       Eq, EkT, values, vlens, wv, partial, tsumb);
    hipLaunchKernelGGL(reduce_kernel, dim3(1024), dim3(256), 0, stream,
                       partial, tsumb, vlens, outp);
  } else {
    hipLaunchKernelGGL(attn_kernel, dim3(512), dim3(256), 0, stream,
                       Eq, EkT, values, vlens, wv, outp);
  }
}

// Round 6
// 103.470 us; speedup vs baseline: 1.0022x; 1.0022x over previous
//
#include <hip/hip_runtime.h>
#include <stddef.h>

// Additive attention: out = softmax_k(mask(sum_h wv_h * tanh(qW_h + kW_h))) @ V
// tanh(q+k) = 1 - 2/(1 + e^{2q} e^{2k})  -> precompute Eq=e^{2q}, Ek=e^{2k};
// score = W0 + sum_h wv2_h * rcp(1 + Eq_h*Ek_h), wv2 = -2*wv, W0 = sum_h wv_h.
// |score| <= W1 = sum_h |wv_h|  ->  softmax without a global max pass:
//   p = exp2((s - W1)*L2E) in (0, 1]; normalize by the total sum at the end.
//
// Pipeline: projq, projk(row-major) -> fused scores+exp+PV partials -> reduce.

__device__ __forceinline__ float fast_rcp(float x)  { return __builtin_amdgcn_rcpf(x); }
__device__ __forceinline__ float fast_exp2(float x) { return __builtin_amdgcn_exp2f(x); }

#define C2F 2.88539008177792681f   // 2*log2(e)
#define L2E 1.44269504088896340f   // log2(e)

// ---------------------------------------------------------------------------
// Projection: P = in[rows x 256] @ W[256 x 64], out = exp2(C2F * P)
// TRANSPOSED: legacy column layout for the fallback kernel only.
// CHECK: per-batch vlens early exit (keys).
// ---------------------------------------------------------------------------
template<bool TRANSPOSED, bool CHECK>
__global__ __launch_bounds__(256)
void proj_kernel(const float* __restrict__ in, const float* __restrict__ W,
                 float* __restrict__ out, const int* __restrict__ vlens,
                 int rowsPerB)
{
  const int t  = threadIdx.x;
  const int b  = blockIdx.x & 15;
  const int rt = blockIdx.x >> 4;
  const int r0 = rt * 64;
  if constexpr (CHECK) {
    if (r0 >= vlens[b]) return;
  }

  __shared__ float4 Wlds[256 * 16];   // [d][h-quad]
  __shared__ float  klds[64 * 36];

  const float4* W4 = (const float4*)W;
  #pragma unroll
  for (int i = 0; i < 16; ++i) Wlds[t + 256 * i] = W4[t + 256 * i];

  const float* inb = in + ((size_t)b * rowsPerB + r0) * 256;
  const int j = t >> 4;
  const int g = t & 15;

  float acc[4][4];
  #pragma unroll
  for (int m = 0; m < 4; ++m)
    acc[m][0] = acc[m][1] = acc[m][2] = acc[m][3] = 0.f;

  for (int dc = 0; dc < 8; ++dc) {
    {
      const int row = t >> 2, cs = (t & 3) * 8;
      const float* s = inb + row * 256 + dc * 32 + cs;
      float4 a0 = *(const float4*)s;
      float4 a1 = *(const float4*)(s + 4);
      float* dst = &klds[row * 36 + cs];
      *(float4*)dst       = a0;
      *(float4*)(dst + 4) = a1;
    }
    __syncthreads();
    #pragma unroll
    for (int d = 0; d < 32; ++d) {
      float4 w4 = Wlds[(dc * 32 + d) * 16 + j];
      #pragma unroll
      for (int m = 0; m < 4; ++m) {
        float kv = klds[(g + 16 * m) * 36 + d];
        acc[m][0] = fmaf(kv, w4.x, acc[m][0]);
        acc[m][1] = fmaf(kv, w4.y, acc[m][1]);
        acc[m][2] = fmaf(kv, w4.z, acc[m][2]);
        acc[m][3] = fmaf(kv, w4.w, acc[m][3]);
      }
    }
    __syncthreads();
  }

  if constexpr (TRANSPOSED) {
    #pragma unroll
    for (int m = 0; m < 4; ++m) {
      int k = r0 + g + 16 * m;
      size_t base = ((size_t)(b * 16 + (k >> 7)) * 64) * 128 + (k & 127);
      #pragma unroll
      for (int i = 0; i < 4; ++i)
        out[base + (size_t)(4 * j + i) * 128] = fast_exp2(C2F * acc[m][i]);
    }
  } else {
    #pragma unroll
    for (int m = 0; m < 4; ++m) {
      int row = r0 + g + 16 * m;
      float4 o;
      o.x = fast_exp2(C2F * acc[m][0]);
      o.y = fast_exp2(C2F * acc[m][1]);
      o.z = fast_exp2(C2F * acc[m][2]);
      o.w = fast_exp2(C2F * acc[m][3]);
      *(float4*)&out[((size_t)b * rowsPerB + row) * 64 + 4 * j] = o;
    }
  }
}

// ---------------------------------------------------------------------------
// Fused scores + exp + PV partial. 512 thr, q-tile 32, k-tile 128.
// grid: blk = qq*256 + g, g=(b,kt): 4 sibling blocks == g (mod 8) -> same XCD.
// Phase 1 (scores): wave owns 4 q, lane owns k-pair; Ek in LDS as [k][64]
//   with XOR-swizzled float4s (conflict-free b128); eq/wv float4 broadcasts.
// Phase 2 (PV): 4 k-groups x 128 v; each V element read once per block;
//   serial-rmw LDS reduction across groups.
// ---------------------------------------------------------------------------
__global__ __launch_bounds__(512, 6)
void scorepv_kernel(const float* __restrict__ Eq, const float* __restrict__ Ek,
                    const float* __restrict__ values, const int* __restrict__ vlens,
                    const float* __restrict__ wv,
                    float* __restrict__ partial, float* __restrict__ tsum)
{
  const int blk = blockIdx.x;
  const int g   = blk & 255;           // (b,kt) group; siblings == g (mod 8)
  const int qq  = blk >> 8;            // 0..3
  const int b   = g >> 4;
  const int kt  = g & 15;
  const int vl  = vlens[b];
  if (kt * 128 >= vl) return;

  __shared__ float ek_lds[128 * 64];   // 32KB; later reused as p_lds / red
  __shared__ float eq_lds[32 * 64];    // 8KB
  __shared__ float wv2_lds[64];

  const int t = threadIdx.x;

  float w0 = 0.f, W1 = 0.f;
  {
    const float4* wv4 = (const float4*)wv;
    #pragma unroll
    for (int u = 0; u < 16; ++u) {
      float4 v = wv4[u];
      w0 += v.x + v.y + v.z + v.w;
      W1 += fabsf(v.x) + fabsf(v.y) + fabsf(v.z) + fabsf(v.w);
    }
  }

  {
    // stage Ek tile [128][64] row-major -> XOR-swizzled float4 rows
    const float4* src = (const float4*)(Ek + ((size_t)(b * 2048 + kt * 128)) * 64);
    float4* ek4 = (float4*)ek_lds;
    #pragma unroll
    for (int i = 0; i < 4; ++i) {
      int idx = t + 512 * i;           // 0..2047
      int k = idx >> 4, hq = idx & 15;
      ek4[k * 16 + (hq ^ (k & 15))] = src[idx];
    }
    const float4* qsrc = (const float4*)(Eq + (size_t)(b * 128 + qq * 32) * 64);
    ((float4*)eq_lds)[t] = qsrc[t];
    if (t < 64) wv2_lds[t] = -2.0f * wv[t];
  }
  __syncthreads();

  const int wave = t >> 6, lane = t & 63;
  const int q0l = wave * 4;            // wave's 4 q rows (exclusive)
  const int kp  = lane * 2;            // lane's k pair
  const int swz0 = kp & 15, swz1 = (kp + 1) & 15;

  float s[4][2];
  #pragma unroll
  for (int q = 0; q < 4; ++q) { s[q][0] = w0; s[q][1] = w0; }

  {
    const float4* ek4 = (const float4*)ek_lds;
    const float4* eq4 = (const float4*)eq_lds;
    const float4* wvq = (const float4*)wv2_lds;
    #pragma unroll 4
    for (int h4 = 0; h4 < 16; ++h4) {
      float4 e0 = ek4[kp * 16 + (h4 ^ swz0)];
      float4 e1 = ek4[(kp + 1) * 16 + (h4 ^ swz1)];
      float4 w4 = wvq[h4];
      #pragma unroll
      for (int q = 0; q < 4; ++q) {
        float4 eq = eq4[(q0l + q) * 16 + h4];
        { float x0 = fmaf(eq.x, e0.x, 1.f), x1 = fmaf(eq.x, e1.x, 1.f);
          float y = w4.x * fast_rcp(x0 * x1);
          s[q][0] = fmaf(x1, y, s[q][0]); s[q][1] = fmaf(x0, y, s[q][1]); }
        { float x0 = fmaf(eq.y, e0.y, 1.f), x1 = fmaf(eq.y, e1.y, 1.f);
          float y = w4.y * fast_rcp(x0 * x1);
          s[q][0] = fmaf(x1, y, s[q][0]); s[q][1] = fmaf(x0, y, s[q][1]); }
        { float x0 = fmaf(eq.z, e0.z, 1.f), x1 = fmaf(eq.z, e1.z, 1.f);
          float y = w4.z * fast_rcp(x0 * x1);
          s[q][0] = fmaf(x1, y, s[q][0]); s[q][1] = fmaf(x0, y, s[q][1]); }
        { float x0 = fmaf(eq.w, e0.w, 1.f), x1 = fmaf(eq.w, e1.w, 1.f);
          float y = w4.w * fast_rcp(x0 * x1);
          s[q][0] = fmaf(x1, y, s[q][0]); s[q][1] = fmaf(x0, y, s[q][1]); }
      }
    }
  }

  // p = exp2((s - W1)*L2E) in (0,1]; masked -> 0 (select, garbage-safe)
  const int kbase = kt * 128 + kp;
  float p[4][2];
  #pragma unroll
  for (int q = 0; q < 4; ++q) {
    p[q][0] = (kbase     < vl) ? fast_exp2((s[q][0] - W1) * L2E) : 0.f;
    p[q][1] = (kbase + 1 < vl) ? fast_exp2((s[q][1] - W1) * L2E) : 0.f;
  }

  // per-tile row sums (wave owns its q rows exclusively)
  #pragma unroll
  for (int q = 0; q < 4; ++q) {
    float e = p[q][0] + p[q][1];
    #pragma unroll
    for (int msk = 1; msk < 64; msk <<= 1) e += __shfl_xor(e, msk, 64);
    if (lane == 0)
      tsum[(size_t)(b * 16 + kt) * 128 + qq * 32 + q0l + q] = e;
  }

  __syncthreads();                     // all ek reads complete before reuse
  float* p_lds = ek_lds;               // [128 k][36 pad]
  *(float4*)&p_lds[kp * 36 + q0l]       = make_float4(p[0][0], p[1][0], p[2][0], p[3][0]);
  *(float4*)&p_lds[(kp + 1) * 36 + q0l] = make_float4(p[0][1], p[1][1], p[2][1], p[3][1]);
  __syncthreads();

  // PV: thread (kg 0..3, v); kg owns 32 k; p float4 broadcasts (wave-uniform)
  const int kg = t >> 7, v = t & 127;
  const int kloc = min(128, vl - kt * 128);
  const int k0 = kg * 32, k1 = min(k0 + 32, kloc);
  const float* vb = values + ((size_t)(b * 2048 + kt * 128)) * 128 + v;
  float acc[32];
  #pragma unroll
  for (int i = 0; i < 32; ++i) acc[i] = 0.f;

  #pragma unroll 2
  for (int k = k0; k < k1; ++k) {
    float vx = vb[(size_t)k * 128];
    const float4* pr = (const float4*)&p_lds[k * 36];
    #pragma unroll
    for (int j = 0; j < 8; ++j) {
      float4 pp = pr[j];
      acc[4*j+0] = fmaf(pp.x, vx, acc[4*j+0]);
      acc[4*j+1] = fmaf(pp.y, vx, acc[4*j+1]);
      acc[4*j+2] = fmaf(pp.z, vx, acc[4*j+2]);
      acc[4*j+3] = fmaf(pp.w, vx, acc[4*j+3]);
    }
  }

  // serial-rmw reduction over kg, then kg0 stores
  __syncthreads();                     // all p reads done
  float* red = ek_lds;                 // [32 q][128 v]
  if (kg == 3) {
    #pragma unroll
    for (int q = 0; q < 32; ++q) red[q * 128 + v] = acc[q];
  }
  __syncthreads();
  if (kg == 2) {
    #pragma unroll
    for (int q = 0; q < 32; ++q) red[q * 128 + v] += acc[q];
  }
  __syncthreads();
  if (kg == 1) {
    #pragma unroll
    for (int q = 0; q < 32; ++q) red[q * 128 + v] += acc[q];
  }
  __syncthreads();
  if (kg == 0) {
    const int qg0 = qq * 32;
    #pragma unroll
    for (int q = 0; q < 32; ++q) {
      float tot = red[q * 128 + v] + acc[q];
      partial[(((size_t)(b * 128 + qg0 + q)) * 16 + kt) * 128 + v] = tot;
    }
  }
}

// ---------------------------------------------------------------------------
// Reduce: out[b][q][v] = sum_kt partial / sum_kt tsum. Block = (b, 2-q), 256 thr.
// ---------------------------------------------------------------------------
__global__ __launch_bounds__(256)
void reduce_kernel(const float* __restrict__ partial, const float* __restrict__ tsum,
                   const int* __restrict__ vlens, float* __restrict__ out)
{
  const int blk = blockIdx.x;          // b*64 + qp
  const int b   = blk >> 6;
  const int q   = (blk & 63) * 2 + (threadIdx.x >> 7);
  const int v   = threadIdx.x & 127;
  const int ntk = (vlens[b] + 127) >> 7;

  float tot = 0.f;
  for (int i = 0; i < ntk; ++i)
    tot += tsum[(size_t)(b * 16 + i) * 128 + q];

  float acc = 0.f;
  const float* pp = partial + ((size_t)(b * 128 + q)) * 16 * 128 + v;
  for (int i = 0; i < ntk; ++i)
    acc += pp[(size_t)i * 128];

  out[((size_t)(b * 128 + q)) * 128 + v] = acc / tot;
}

// ---------------------------------------------------------------------------
// Fallback fused kernel (round-1, known-correct) for small ws_size.
// Uses the TRANSPOSED Ek layout.
// ---------------------------------------------------------------------------
__global__ __launch_bounds__(256)
void attn_kernel(const float* __restrict__ Eq, const float* __restrict__ EkT,
                 const float* __restrict__ values, const int* __restrict__ vlens,
                 const float* __restrict__ wv, float* __restrict__ out)
{
  const int t    = threadIdx.x;
  const int b    = blockIdx.x & 15;
  const int qt   = blockIdx.x >> 4;
  const int wave = t >> 6;
  const int lane = t & 63;

  __shared__ float4 sc4[512 * 4];
  __shared__ float  pvp[128 * 5];
  __shared__ float  linvs[4];

  const int vl = vlens[b];

  float eqv[64], wv2[64];
  float w0 = 0.f;
  {
    const float4* eq4 = (const float4*)(Eq + (size_t)(b * 128 + qt * 4 + wave) * 64);
    const float4* wv4 = (const float4*)wv;
    #pragma unroll
    for (int u = 0; u < 16; ++u) {
      float4 e = eq4[u], v = wv4[u];
      eqv[4*u+0] = e.x; eqv[4*u+1] = e.y; eqv[4*u+2] = e.z; eqv[4*u+3] = e.w;
      wv2[4*u+0] = -2.f * v.x; wv2[4*u+1] = -2.f * v.y;
      wv2[4*u+2] = -2.f * v.z; wv2[4*u+3] = -2.f * v.w;
      w0 += v.x + v.y + v.z + v.w;
    }
  }

  const int ktiles = (vl + 127) >> 7;
  const int kp = 2 * lane;
  for (int kt = 0; kt < ktiles; ++kt) {
    const float* tb = EkT + ((size_t)(b * 16 + kt) * 64) * 128 + kp;
    float s0 = w0, s1 = w0;
    #pragma unroll
    for (int h = 0; h < 64; ++h) {
      float2 ek = *(const float2*)(tb + (size_t)h * 128);
      float r0 = fast_rcp(fmaf(eqv[h], ek.x, 1.0f));
      float r1 = fast_rcp(fmaf(eqv[h], ek.y, 1.0f));
      s0 = fmaf(wv2[h], r0, s0);
      s1 = fmaf(wv2[h], r1, s1);
    }
    int k = kt * 128 + kp;
    if (k     >= vl) s0 = -1e9f;
    if (k + 1 >= vl) s1 = -1e9f;
    float* scf = (float*)sc4;
    *(float2*)(scf + (((k >> 2) * 4 + wave) * 4 + (k & 3))) = make_float2(s0, s1);
  }

  const int nq4 = (vl + 3) >> 2;
  float mx = -3e38f;
  for (int Q = lane; Q < nq4; Q += 64) {
    float4 f = sc4[Q * 4 + wave];
    mx = fmaxf(mx, fmaxf(fmaxf(f.x, f.y), fmaxf(f.z, f.w)));
  }
  #pragma unroll
  for (int msk = 1; msk < 64; msk <<= 1) mx = fmaxf(mx, __shfl_xor(mx, msk, 64));
  float lsum = 0.f;
  for (int Q = lane; Q < nq4; Q += 64) {
    float4 f = sc4[Q * 4 + wave];
    f.x = fast_exp2((f.x - mx) * L2E);
    f.y = fast_exp2((f.y - mx) * L2E);
    f.z = fast_exp2((f.z - mx) * L2E);
    f.w = fast_exp2((f.w - mx) * L2E);
    sc4[Q * 4 + wave] = f;
    lsum += f.x + f.y + f.z + f.w;
  }
  #pragma unroll
  for (int msk = 1; msk < 64; msk <<= 1) lsum += __shfl_xor(lsum, msk, 64);
  if (lane == 0) linvs[wave] = fast_rcp(lsum);
  __syncthreads();

  const int grp = t >> 7, v = t & 127;
  float acc[4] = {0.f, 0.f, 0.f, 0.f};
  const float* vb = values + (size_t)b * 2048 * 128 + v;
  for (int Q = grp; Q < nq4; Q += 2) {
    float4 p0 = sc4[Q * 4 + 0], p1 = sc4[Q * 4 + 1];
    float4 p2 = sc4[Q * 4 + 2], p3 = sc4[Q * 4 + 3];
    const float* vk = vb + (size_t)(Q * 4) * 128;
    float x;
    x = vk[0];
    acc[0]=fmaf(p0.x,x,acc[0]); acc[1]=fmaf(p1.x,x,acc[1]);
    acc[2]=fmaf(p2.x,x,acc[2]); acc[3]=fmaf(p3.x,x,acc[3]);
    x = vk[128];
    acc[0]=fmaf(p0.y,x,acc[0]); acc[1]=fmaf(p1.y,x,acc[1]);
    acc[2]=fmaf(p2.y,x,acc[2]); acc[3]=fmaf(p3.y,x,acc[3]);
    x = vk[256];
    acc[0]=fmaf(p0.z,x,acc[0]); acc[1]=fmaf(p1.z,x,acc[1]);
    acc[2]=fmaf(p2.z,x,acc[2]); acc[3]=fmaf(p3.z,x,acc[3]);
    x = vk[384];
    acc[0]=fmaf(p0.w,x,acc[0]); acc[1]=fmaf(p1.w,x,acc[1]);
    acc[2]=fmaf(p2.w,x,acc[2]); acc[3]=fmaf(p3.w,x,acc[3]);
  }
  if (grp == 1) {
    #pragma unroll
    for (int qq = 0; qq < 4; ++qq) pvp[v * 5 + qq] = acc[qq];
  }
  __syncthreads();
  if (grp == 0) {
    #pragma unroll
    for (int qq = 0; qq < 4; ++qq) {
      float tot = acc[qq] + pvp[v * 5 + qq];
      out[((size_t)(b * 128) + qt * 4 + qq) * 128 + v] = tot * linvs[qq];
    }
  }
}

// ---------------------------------------------------------------------------
extern "C" void kernel_launch(void* const* d_in, const int* in_sizes, int n_in,
                              void* d_out, int out_size, void* d_ws, size_t ws_size,
                              hipStream_t stream) {
  const float* queries = (const float*)d_in[0];   // [16][128][256]
  const float* keys    = (const float*)d_in[1];   // [16][2048][256]
  const float* values  = (const float*)d_in[2];   // [16][2048][128]
  const int*   vlens   = (const int*)d_in[3];     // [16]
  const float* Wq      = (const float*)d_in[4];   // [256][64]
  const float* Wk      = (const float*)d_in[5];   // [256][64]
  const float* wv      = (const float*)d_in[6];   // [64]
  float* outp = (float*)d_out;

  float* base    = (float*)d_ws;
  float* Eq      = base;                 // 131072 f
  float* Ek      = base + 131072;        // 2097152 f  (row-major [b][k][h])
  float* tsumb   = base + 2228224;       // 32768 f    [b][kt][q]
  float* partial = base + 2260992;       // 4194304 f  [b][q][kt][v]
  const size_t need = (size_t)(2260992 + 4194304) * 4;

  hipLaunchKernelGGL((proj_kernel<false, false>), dim3(32), dim3(256), 0, stream,
                     queries, Wq, Eq, (const int*)nullptr, 128);

  if (ws_size >= need) {
    hipLaunchKernelGGL((proj_kernel<false, true>), dim3(512), dim3(256), 0, stream,
                       keys, Wk, Ek, vlens, 2048);
    hipLaunchKernelGGL(scorepv_kernel, dim3(1024), dim3(512), 0, stream,
                       Eq, Ek, values, vlens, wv, partial, tsumb);
    hipLaunchKernelGGL(reduce_kernel, dim3(1024), dim3(256), 0, stream,
                       partial, tsumb, vlens, outp);
  } else {
    hipLaunchKernelGGL((proj_kernel<true, true>), dim3(512), dim3(256), 0, stream,
                       keys, Wk, Ek, vlens, 2048);
    hipLaunchKernelGGL(attn_kernel, dim3(512), dim3(256), 0, stream,
                       Eq, Ek, values, vlens, wv, outp);
  }
}

// Round 7
// 99.359 us; speedup vs baseline: 1.0436x; 1.0414x over previous
//
#include <hip/hip_runtime.h>
#include <stddef.h>

// Additive attention: out = softmax_k(mask(sum_h wv_h * tanh(qW_h + kW_h))) @ V
// tanh(q+k) = 1 - 2/(1 + e^{2q} e^{2k})  -> precompute Eq=e^{2q}, Ek=e^{2k};
// score = W0 + sum_h wv2_h * rcp(1 + Eq_h*Ek_h), wv2 = -2*wv, W0 = sum_h wv_h.
// h-paired rcp: 1/x0 + 1/x1 terms share one rcp via y = rcp(x0*x1).
// |score| <= W1 = sum_h |wv_h| -> p = exp2((s-W1)*L2E) in (0,1], no max pass.
//
// scorepv round-7 structure: eq/wv on the SCALAR pipe (uniform s_load -> SGPR
// operand of v_fma), ek on LDS [h][128] contiguous b64 (conflict-free). This
// removes ~60% of vector-LDS traffic; score loop becomes VALU-bound.

__device__ __forceinline__ float fast_rcp(float x)  { return __builtin_amdgcn_rcpf(x); }
__device__ __forceinline__ float fast_exp2(float x) { return __builtin_amdgcn_exp2f(x); }

#define C2F 2.88539008177792681f   // 2*log2(e)
#define L2E 1.44269504088896340f   // log2(e)

// ---------------------------------------------------------------------------
// Projection: P = in[rows x 256] @ W[256 x 64], out = exp2(C2F * P)
// TRANSPOSED: legacy column layout for the fallback kernel only.
// CHECK: per-batch vlens early exit (keys).
// ---------------------------------------------------------------------------
template<bool TRANSPOSED, bool CHECK>
__global__ __launch_bounds__(256)
void proj_kernel(const float* __restrict__ in, const float* __restrict__ W,
                 float* __restrict__ out, const int* __restrict__ vlens,
                 int rowsPerB)
{
  const int t  = threadIdx.x;
  const int b  = blockIdx.x & 15;
  const int rt = blockIdx.x >> 4;
  const int r0 = rt * 64;
  if constexpr (CHECK) {
    if (r0 >= vlens[b]) return;
  }

  __shared__ float4 Wlds[256 * 16];   // [d][h-quad]
  __shared__ float  klds[64 * 36];

  const float4* W4 = (const float4*)W;
  #pragma unroll
  for (int i = 0; i < 16; ++i) Wlds[t + 256 * i] = W4[t + 256 * i];

  const float* inb = in + ((size_t)b * rowsPerB + r0) * 256;
  const int j = t >> 4;
  const int g = t & 15;

  float acc[4][4];
  #pragma unroll
  for (int m = 0; m < 4; ++m)
    acc[m][0] = acc[m][1] = acc[m][2] = acc[m][3] = 0.f;

  for (int dc = 0; dc < 8; ++dc) {
    {
      const int row = t >> 2, cs = (t & 3) * 8;
      const float* s = inb + row * 256 + dc * 32 + cs;
      float4 a0 = *(const float4*)s;
      float4 a1 = *(const float4*)(s + 4);
      float* dst = &klds[row * 36 + cs];
      *(float4*)dst       = a0;
      *(float4*)(dst + 4) = a1;
    }
    __syncthreads();
    #pragma unroll
    for (int d = 0; d < 32; ++d) {
      float4 w4 = Wlds[(dc * 32 + d) * 16 + j];
      #pragma unroll
      for (int m = 0; m < 4; ++m) {
        float kv = klds[(g + 16 * m) * 36 + d];
        acc[m][0] = fmaf(kv, w4.x, acc[m][0]);
        acc[m][1] = fmaf(kv, w4.y, acc[m][1]);
        acc[m][2] = fmaf(kv, w4.z, acc[m][2]);
        acc[m][3] = fmaf(kv, w4.w, acc[m][3]);
      }
    }
    __syncthreads();
  }

  if constexpr (TRANSPOSED) {
    #pragma unroll
    for (int m = 0; m < 4; ++m) {
      int k = r0 + g + 16 * m;
      size_t base = ((size_t)(b * 16 + (k >> 7)) * 64) * 128 + (k & 127);
      #pragma unroll
      for (int i = 0; i < 4; ++i)
        out[base + (size_t)(4 * j + i) * 128] = fast_exp2(C2F * acc[m][i]);
    }
  } else {
    #pragma unroll
    for (int m = 0; m < 4; ++m) {
      int row = r0 + g + 16 * m;
      float4 o;
      o.x = fast_exp2(C2F * acc[m][0]);
      o.y = fast_exp2(C2F * acc[m][1]);
      o.z = fast_exp2(C2F * acc[m][2]);
      o.w = fast_exp2(C2F * acc[m][3]);
      *(float4*)&out[((size_t)b * rowsPerB + row) * 64 + 4 * j] = o;
    }
  }
}

// ---------------------------------------------------------------------------
// Fused scores + exp + PV partial. 256 thr = 4 waves; wave owns 4 q.
// grid: blk = qq*256 + g, g = kt*16 + b  (XCD = b&7: kt-balanced; 8 qq
// siblings of one (b,kt) land on the same XCD -> Ek/V L2 reuse).
// Score phase: lane owns k-pair; ek from LDS [h][128] (contiguous b64);
// eq/wv from global via wave-uniform scalar loads (SGPR operands).
// PV phase: 2 k-groups x 128 v, V read once per block, acc[16].
// ---------------------------------------------------------------------------
__global__ __launch_bounds__(256, 4)
void scorepv_kernel(const float* __restrict__ Eq, const float* __restrict__ Ek,
                    const float* __restrict__ values, const int* __restrict__ vlens,
                    const float* __restrict__ wv,
                    float* __restrict__ partial, float* __restrict__ tsum)
{
  const int blk = blockIdx.x;
  const int g   = blk & 255;           // g = kt*16 + b
  const int qq  = blk >> 8;            // 0..7 (16-q tile)
  const int kt  = g >> 4;
  const int b   = g & 15;
  const int vl  = vlens[b];
  if (kt * 128 >= vl) return;

  __shared__ float ek_lds[64 * 128];   // [h][k] 32KB; reused as p_lds + red

  const int t = threadIdx.x;

  // stage Ek [128k][64h] -> ek_lds[h][k]  (transpose; conflict-free b64 writes)
  {
    const float4* src = (const float4*)(Ek + ((size_t)(b * 2048 + kt * 128)) * 64);
    #pragma unroll
    for (int i = 0; i < 4; ++i) {
      int u   = t + 256 * i;           // 0..1023
      int kp2 = u & 63;                // k-pair
      int hq  = u >> 6;                // h-quad 0..15
      float4 a0 = src[(2 * kp2) * 16 + hq];
      float4 a1 = src[(2 * kp2 + 1) * 16 + hq];
      *(float2*)&ek_lds[(4 * hq + 0) * 128 + 2 * kp2] = make_float2(a0.x, a1.x);
      *(float2*)&ek_lds[(4 * hq + 1) * 128 + 2 * kp2] = make_float2(a0.y, a1.y);
      *(float2*)&ek_lds[(4 * hq + 2) * 128 + 2 * kp2] = make_float2(a0.z, a1.z);
      *(float2*)&ek_lds[(4 * hq + 3) * 128 + 2 * kp2] = make_float2(a0.w, a1.w);
    }
  }

  // w0 = sum wv, W1 = sum |wv| (uniform -> scalar pipe)
  float w0 = 0.f, W1 = 0.f;
  #pragma unroll
  for (int u = 0; u < 16; ++u) {
    float4 v = ((const float4*)wv)[u];
    w0 += v.x + v.y + v.z + v.w;
    W1 += fabsf(v.x) + fabsf(v.y) + fabsf(v.z) + fabsf(v.w);
  }

  __syncthreads();

  const int wave_u = __builtin_amdgcn_readfirstlane(t >> 6);  // uniform wave id
  const int lane   = t & 63;
  const int q0g    = qq * 16 + wave_u * 4;   // wave's 4 exclusive q rows
  const int kp     = lane * 2;               // lane's k pair
  const float* eqb = Eq + (size_t)(b * 128 + q0g) * 64;

  float s[4][2];
  #pragma unroll
  for (int q = 0; q < 4; ++q) { s[q][0] = w0; s[q][1] = w0; }

  #pragma unroll 4
  for (int hp = 0; hp < 32; ++hp) {          // h-pairs
    float2 ekA = *(const float2*)&ek_lds[(2 * hp) * 128 + kp];     // h=2hp
    float2 ekB = *(const float2*)&ek_lds[(2 * hp + 1) * 128 + kp]; // h=2hp+1
    float2 wvp = *(const float2*)&wv[2 * hp];  // uniform -> SGPR
    float wa = -2.0f * wvp.x, wb = -2.0f * wvp.y;
    #pragma unroll
    for (int q = 0; q < 4; ++q) {
      float2 eqp = *(const float2*)&eqb[q * 64 + 2 * hp];  // uniform -> s_load
      {  // k = kp
        float x0 = fmaf(eqp.x, ekA.x, 1.f);
        float x1 = fmaf(eqp.y, ekB.x, 1.f);
        float y  = fast_rcp(x0 * x1);
        float a  = wb * x0;
        a = fmaf(wa, x1, a);
        s[q][0] = fmaf(a, y, s[q][0]);
      }
      {  // k = kp+1
        float x0 = fmaf(eqp.x, ekA.y, 1.f);
        float x1 = fmaf(eqp.y, ekB.y, 1.f);
        float y  = fast_rcp(x0 * x1);
        float a  = wb * x0;
        a = fmaf(wa, x1, a);
        s[q][1] = fmaf(a, y, s[q][1]);
      }
    }
  }

  // p = exp2((s - W1)*L2E) in (0,1]; masked -> 0 (select, garbage/NaN-safe)
  const int kbase = kt * 128 + kp;
  float p[4][2];
  #pragma unroll
  for (int q = 0; q < 4; ++q) {
    p[q][0] = (kbase     < vl) ? fast_exp2((s[q][0] - W1) * L2E) : 0.f;
    p[q][1] = (kbase + 1 < vl) ? fast_exp2((s[q][1] - W1) * L2E) : 0.f;
  }

  // per-tile row sums (wave owns its q rows exclusively)
  #pragma unroll
  for (int q = 0; q < 4; ++q) {
    float e = p[q][0] + p[q][1];
    #pragma unroll
    for (int m = 1; m < 64; m <<= 1) e += __shfl_xor(e, m, 64);
    if (lane == 0) tsum[(size_t)(b * 16 + kt) * 128 + q0g + q] = e;
  }

  __syncthreads();                     // all ek reads complete before reuse
  float* p_lds = ek_lds;               // [128 k][20 pad]
  const int q0l = wave_u * 4;
  *(float4*)&p_lds[kp * 20 + q0l]       = make_float4(p[0][0], p[1][0], p[2][0], p[3][0]);
  *(float4*)&p_lds[(kp + 1) * 20 + q0l] = make_float4(p[0][1], p[1][1], p[2][1], p[3][1]);
  __syncthreads();

  // PV: thread (kg 0..1, v); kg owns 64 k; p float4 wave-uniform broadcasts
  const int kg = t >> 7, v = t & 127;
  const int kloc = min(128, vl - kt * 128);
  const int k0 = kg * 64, k1 = min(k0 + 64, kloc);
  const float* vb = values + ((size_t)(b * 2048 + kt * 128)) * 128 + v;
  float acc[16];
  #pragma unroll
  for (int i = 0; i < 16; ++i) acc[i] = 0.f;

  #pragma unroll 4
  for (int k = k0; k < k1; ++k) {
    float vx = vb[(size_t)k * 128];
    const float* pr = &p_lds[k * 20];
    float4 p0 = *(const float4*)&pr[0];
    float4 p1 = *(const float4*)&pr[4];
    float4 p2 = *(const float4*)&pr[8];
    float4 p3 = *(const float4*)&pr[12];
    acc[ 0] = fmaf(p0.x, vx, acc[ 0]); acc[ 1] = fmaf(p0.y, vx, acc[ 1]);
    acc[ 2] = fmaf(p0.z, vx, acc[ 2]); acc[ 3] = fmaf(p0.w, vx, acc[ 3]);
    acc[ 4] = fmaf(p1.x, vx, acc[ 4]); acc[ 5] = fmaf(p1.y, vx, acc[ 5]);
    acc[ 6] = fmaf(p1.z, vx, acc[ 6]); acc[ 7] = fmaf(p1.w, vx, acc[ 7]);
    acc[ 8] = fmaf(p2.x, vx, acc[ 8]); acc[ 9] = fmaf(p2.y, vx, acc[ 9]);
    acc[10] = fmaf(p2.z, vx, acc[10]); acc[11] = fmaf(p2.w, vx, acc[11]);
    acc[12] = fmaf(p3.x, vx, acc[12]); acc[13] = fmaf(p3.y, vx, acc[13]);
    acc[14] = fmaf(p3.z, vx, acc[14]); acc[15] = fmaf(p3.w, vx, acc[15]);
  }

  // cross-kg reduction: red region does NOT alias p_lds (2560+2048 <= 8192)
  float* red = ek_lds + 128 * 20;      // [16 q][128 v]
  if (kg == 1) {
    #pragma unroll
    for (int q = 0; q < 16; ++q) red[q * 128 + v] = acc[q];
  }
  __syncthreads();
  if (kg == 0) {
    #pragma unroll
    for (int q = 0; q < 16; ++q) {
      float tot = acc[q] + red[q * 128 + v];
      partial[(((size_t)(b * 128 + qq * 16 + q)) * 16 + kt) * 128 + v] = tot;
    }
  }
}

// ---------------------------------------------------------------------------
// Reduce: out[b][q][v] = sum_kt partial / sum_kt tsum. Block = (b, 2-q), 256 thr.
// ---------------------------------------------------------------------------
__global__ __launch_bounds__(256)
void reduce_kernel(const float* __restrict__ partial, const float* __restrict__ tsum,
                   const int* __restrict__ vlens, float* __restrict__ out)
{
  const int blk = blockIdx.x;          // b*64 + qp
  const int b   = blk >> 6;
  const int q   = (blk & 63) * 2 + (threadIdx.x >> 7);
  const int v   = threadIdx.x & 127;
  const int ntk = (vlens[b] + 127) >> 7;

  float tot = 0.f;
  for (int i = 0; i < ntk; ++i)
    tot += tsum[(size_t)(b * 16 + i) * 128 + q];

  float acc = 0.f;
  const float* pp = partial + ((size_t)(b * 128 + q)) * 16 * 128 + v;
  for (int i = 0; i < ntk; ++i)
    acc += pp[(size_t)i * 128];

  out[((size_t)(b * 128 + q)) * 128 + v] = acc / tot;
}

// ---------------------------------------------------------------------------
// Fallback fused kernel (round-1, known-correct) for small ws_size.
// Uses the TRANSPOSED Ek layout.
// ---------------------------------------------------------------------------
__global__ __launch_bounds__(256)
void attn_kernel(const float* __restrict__ Eq, const float* __restrict__ EkT,
                 const float* __restrict__ values, const int* __restrict__ vlens,
                 const float* __restrict__ wv, float* __restrict__ out)
{
  const int t    = threadIdx.x;
  const int b    = blockIdx.x & 15;
  const int qt   = blockIdx.x >> 4;
  const int wave = t >> 6;
  const int lane = t & 63;

  __shared__ float4 sc4[512 * 4];
  __shared__ float  pvp[128 * 5];
  __shared__ float  linvs[4];

  const int vl = vlens[b];

  float eqv[64], wv2[64];
  float w0 = 0.f;
  {
    const float4* eq4 = (const float4*)(Eq + (size_t)(b * 128 + qt * 4 + wave) * 64);
    const float4* wv4 = (const float4*)wv;
    #pragma unroll
    for (int u = 0; u < 16; ++u) {
      float4 e = eq4[u], v = wv4[u];
      eqv[4*u+0] = e.x; eqv[4*u+1] = e.y; eqv[4*u+2] = e.z; eqv[4*u+3] = e.w;
      wv2[4*u+0] = -2.f * v.x; wv2[4*u+1] = -2.f * v.y;
      wv2[4*u+2] = -2.f * v.z; wv2[4*u+3] = -2.f * v.w;
      w0 += v.x + v.y + v.z + v.w;
    }
  }

  const int ktiles = (vl + 127) >> 7;
  const int kp = 2 * lane;
  for (int kt = 0; kt < ktiles; ++kt) {
    const float* tb = EkT + ((size_t)(b * 16 + kt) * 64) * 128 + kp;
    float s0 = w0, s1 = w0;
    #pragma unroll
    for (int h = 0; h < 64; ++h) {
      float2 ek = *(const float2*)(tb + (size_t)h * 128);
      float r0 = fast_rcp(fmaf(eqv[h], ek.x, 1.0f));
      float r1 = fast_rcp(fmaf(eqv[h], ek.y, 1.0f));
      s0 = fmaf(wv2[h], r0, s0);
      s1 = fmaf(wv2[h], r1, s1);
    }
    int k = kt * 128 + kp;
    if (k     >= vl) s0 = -1e9f;
    if (k + 1 >= vl) s1 = -1e9f;
    float* scf = (float*)sc4;
    *(float2*)(scf + (((k >> 2) * 4 + wave) * 4 + (k & 3))) = make_float2(s0, s1);
  }

  const int nq4 = (vl + 3) >> 2;
  float mx = -3e38f;
  for (int Q = lane; Q < nq4; Q += 64) {
    float4 f = sc4[Q * 4 + wave];
    mx = fmaxf(mx, fmaxf(fmaxf(f.x, f.y), fmaxf(f.z, f.w)));
  }
  #pragma unroll
  for (int msk = 1; msk < 64; msk <<= 1) mx = fmaxf(mx, __shfl_xor(mx, msk, 64));
  float lsum = 0.f;
  for (int Q = lane; Q < nq4; Q += 64) {
    float4 f = sc4[Q * 4 + wave];
    f.x = fast_exp2((f.x - mx) * L2E);
    f.y = fast_exp2((f.y - mx) * L2E);
    f.z = fast_exp2((f.z - mx) * L2E);
    f.w = fast_exp2((f.w - mx) * L2E);
    sc4[Q * 4 + wave] = f;
    lsum += f.x + f.y + f.z + f.w;
  }
  #pragma unroll
  for (int msk = 1; msk < 64; msk <<= 1) lsum += __shfl_xor(lsum, msk, 64);
  if (lane == 0) linvs[wave] = fast_rcp(lsum);
  __syncthreads();

  const int grp = t >> 7, v = t & 127;
  float acc[4] = {0.f, 0.f, 0.f, 0.f};
  const float* vb = values + (size_t)b * 2048 * 128 + v;
  for (int Q = grp; Q < nq4; Q += 2) {
    float4 p0 = sc4[Q * 4 + 0], p1 = sc4[Q * 4 + 1];
    float4 p2 = sc4[Q * 4 + 2], p3 = sc4[Q * 4 + 3];
    const float* vk = vb + (size_t)(Q * 4) * 128;
    float x;
    x = vk[0];
    acc[0]=fmaf(p0.x,x,acc[0]); acc[1]=fmaf(p1.x,x,acc[1]);
    acc[2]=fmaf(p2.x,x,acc[2]); acc[3]=fmaf(p3.x,x,acc[3]);
    x = vk[128];
    acc[0]=fmaf(p0.y,x,acc[0]); acc[1]=fmaf(p1.y,x,acc[1]);
    acc[2]=fmaf(p2.y,x,acc[2]); acc[3]=fmaf(p3.y,x,acc[3]);
    x = vk[256];
    acc[0]=fmaf(p0.z,x,acc[0]); acc[1]=fmaf(p1.z,x,acc[1]);
    acc[2]=fmaf(p2.z,x,acc[2]); acc[3]=fmaf(p3.z,x,acc[3]);
    x = vk[384];
    acc[0]=fmaf(p0.w,x,acc[0]); acc[1]=fmaf(p1.w,x,acc[1]);
    acc[2]=fmaf(p2.w,x,acc[2]); acc[3]=fmaf(p3.w,x,acc[3]);
  }
  if (grp == 1) {
    #pragma unroll
    for (int qq = 0; qq < 4; ++qq) pvp[v * 5 + qq] = acc[qq];
  }
  __syncthreads();
  if (grp == 0) {
    #pragma unroll
    for (int qq = 0; qq < 4; ++qq) {
      float tot = acc[qq] + pvp[v * 5 + qq];
      out[((size_t)(b * 128) + qt * 4 + qq) * 128 + v] = tot * linvs[qq];
    }
  }
}

// ---------------------------------------------------------------------------
extern "C" void kernel_launch(void* const* d_in, const int* in_sizes, int n_in,
                              void* d_out, int out_size, void* d_ws, size_t ws_size,
                              hipStream_t stream) {
  const float* queries = (const float*)d_in[0];   // [16][128][256]
  const float* keys    = (const float*)d_in[1];   // [16][2048][256]
  const float* values  = (const float*)d_in[2];   // [16][2048][128]
  const int*   vlens   = (const int*)d_in[3];     // [16]
  const float* Wq      = (const float*)d_in[4];   // [256][64]
  const float* Wk      = (const float*)d_in[5];   // [256][64]
  const float* wv      = (const float*)d_in[6];   // [64]
  float* outp = (float*)d_out;

  float* base    = (float*)d_ws;
  float* Eq      = base;                 // 131072 f
  float* Ek      = base + 131072;        // 2097152 f  (row-major [b][k][h])
  float* tsumb   = base + 2228224;       // 32768 f    [b][kt][q]
  float* partial = base + 2260992;       // 4194304 f  [b][q][kt][v]
  const size_t need = (size_t)(2260992 + 4194304) * 4;

  hipLaunchKernelGGL((proj_kernel<false, false>), dim3(32), dim3(256), 0, stream,
                     queries, Wq, Eq, (const int*)nullptr, 128);

  if (ws_size >= need) {
    hipLaunchKernelGGL((proj_kernel<false, true>), dim3(512), dim3(256), 0, stream,
                       keys, Wk, Ek, vlens, 2048);
    hipLaunchKernelGGL(scorepv_kernel, dim3(2048), dim3(256), 0, stream,
                       Eq, Ek, values, vlens, wv, partial, tsumb);
    hipLaunchKernelGGL(reduce_kernel, dim3(1024), dim3(256), 0, stream,
                       partial, tsumb, vlens, outp);
  } else {
    hipLaunchKernelGGL((proj_kernel<true, true>), dim3(512), dim3(256), 0, stream,
                       keys, Wk, Ek, vlens, 2048);
    hipLaunchKernelGGL(attn_kernel, dim3(512), dim3(256), 0, stream,
                       Eq, Ek, values, vlens, wv, outp);
  }
}

// Round 8
// 84.566 us; speedup vs baseline: 1.2262x; 1.1749x over previous
//
#include <hip/hip_runtime.h>
#include <stddef.h>

// Additive attention: out = softmax_k(mask(sum_h wv_h * tanh(qW_h + kW_h))) @ V
// tanh(q+k) = 1 - 2/(1 + e^{2q} e^{2k})  -> precompute Eq=e^{2q}, Ek=e^{2k};
// score = W0 + sum_h wv2_h * rcp(1 + Eq_h*Ek_h), wv2 = -2*wv, W0 = sum_h wv_h.
// h-paired rcp: 1/x0 + 1/x1 terms share one rcp via y = rcp(x0*x1).
// |score| <= W1 = sum_h |wv_h| -> p = exp2((s-W1)*L2E) in (0,1], no max pass.
//
// Round-8: XCD-balanced dispatch (qq in low 3 bits -> every XCD gets every
// active (b,kt) group once; work per XCD identical by construction). The
// R5-R7 plateau was inter-XCD imbalance (XCD = b&7 confined batches).

__device__ __forceinline__ float fast_rcp(float x)  { return __builtin_amdgcn_rcpf(x); }
__device__ __forceinline__ float fast_exp2(float x) { return __builtin_amdgcn_exp2f(x); }

#define C2F 2.88539008177792681f   // 2*log2(e)
#define L2E 1.44269504088896340f   // log2(e)

// ---------------------------------------------------------------------------
// Shared projection body: P = in[64 rows x 256] @ W[256 x 64],
// out = exp2(C2F*P) row-major [row][64]. (TRANSPOSED variant for fallback.)
// ---------------------------------------------------------------------------
template<bool TRANSPOSED>
__device__ __forceinline__
void proj_body(const float* __restrict__ inb, const float* __restrict__ W,
               float* __restrict__ out, int b, int r0, int rowsPerB, int t)
{
  __shared__ float4 Wlds[256 * 16];   // [d][h-quad]
  __shared__ float  klds[64 * 36];

  const float4* W4 = (const float4*)W;
  #pragma unroll
  for (int i = 0; i < 16; ++i) Wlds[t + 256 * i] = W4[t + 256 * i];

  const int j = t >> 4;
  const int g = t & 15;

  float acc[4][4];
  #pragma unroll
  for (int m = 0; m < 4; ++m)
    acc[m][0] = acc[m][1] = acc[m][2] = acc[m][3] = 0.f;

  for (int dc = 0; dc < 8; ++dc) {
    {
      const int row = t >> 2, cs = (t & 3) * 8;
      const float* s = inb + row * 256 + dc * 32 + cs;
      float4 a0 = *(const float4*)s;
      float4 a1 = *(const float4*)(s + 4);
      float* dst = &klds[row * 36 + cs];
      *(float4*)dst       = a0;
      *(float4*)(dst + 4) = a1;
    }
    __syncthreads();
    #pragma unroll
    for (int d = 0; d < 32; ++d) {
      float4 w4 = Wlds[(dc * 32 + d) * 16 + j];
      #pragma unroll
      for (int m = 0; m < 4; ++m) {
        float kv = klds[(g + 16 * m) * 36 + d];
        acc[m][0] = fmaf(kv, w4.x, acc[m][0]);
        acc[m][1] = fmaf(kv, w4.y, acc[m][1]);
        acc[m][2] = fmaf(kv, w4.z, acc[m][2]);
        acc[m][3] = fmaf(kv, w4.w, acc[m][3]);
      }
    }
    __syncthreads();
  }

  if constexpr (TRANSPOSED) {
    #pragma unroll
    for (int m = 0; m < 4; ++m) {
      int k = r0 + g + 16 * m;
      size_t base = ((size_t)(b * 16 + (k >> 7)) * 64) * 128 + (k & 127);
      #pragma unroll
      for (int i = 0; i < 4; ++i)
        out[base + (size_t)(4 * j + i) * 128] = fast_exp2(C2F * acc[m][i]);
    }
  } else {
    #pragma unroll
    for (int m = 0; m < 4; ++m) {
      int row = r0 + g + 16 * m;
      float4 o;
      o.x = fast_exp2(C2F * acc[m][0]);
      o.y = fast_exp2(C2F * acc[m][1]);
      o.z = fast_exp2(C2F * acc[m][2]);
      o.w = fast_exp2(C2F * acc[m][3]);
      *(float4*)&out[((size_t)b * rowsPerB + row) * 64 + 4 * j] = o;
    }
  }
}

// Merged q+k projection: blocks 0..511 keys (vlens early-exit), 512..543 queries.
__global__ __launch_bounds__(256)
void proj_qk_kernel(const float* __restrict__ queries, const float* __restrict__ keys,
                    const float* __restrict__ Wq, const float* __restrict__ Wk,
                    float* __restrict__ Eq, float* __restrict__ Ek,
                    const int* __restrict__ vlens)
{
  const int blk = blockIdx.x;
  const bool isq = blk >= 512;
  const int idx = isq ? blk - 512 : blk;
  const int b   = idx & 15;
  const int rt  = idx >> 4;
  const int r0  = rt * 64;
  if (!isq && r0 >= vlens[b]) return;

  const float* in  = isq ? queries : keys;
  const float* W   = isq ? Wq : Wk;
  float* out       = isq ? Eq : Ek;
  const int rowsPerB = isq ? 128 : 2048;
  proj_body<false>(in + ((size_t)b * rowsPerB + r0) * 256, W, out, b, r0, rowsPerB,
                   threadIdx.x);
}

// Fallback projections (legacy layouts)
template<bool TRANSPOSED, bool CHECK>
__global__ __launch_bounds__(256)
void proj_kernel(const float* __restrict__ in, const float* __restrict__ W,
                 float* __restrict__ out, const int* __restrict__ vlens,
                 int rowsPerB)
{
  const int t  = threadIdx.x;
  const int b  = blockIdx.x & 15;
  const int rt = blockIdx.x >> 4;
  const int r0 = rt * 64;
  if constexpr (CHECK) {
    if (r0 >= vlens[b]) return;
  }
  proj_body<TRANSPOSED>(in + ((size_t)b * rowsPerB + r0) * 256, W, out, b, r0,
                        rowsPerB, t);
}

// ---------------------------------------------------------------------------
// Fused scores + exp + PV partial. 256 thr = 4 waves; wave owns 4 q.
// grid: blk = g*8 + qq, g = kt*16 + b. XCD = blk%8 = qq -> every XCD runs
// every active g exactly once (perfect balance regardless of vlens).
// Score phase: lane owns k-pair; ek from LDS [h][128] (contiguous b64);
// eq/wv via wave-uniform scalar loads (SGPR operands of v_fma).
// PV phase: 2 k-groups x 128 v, V read once per block, acc[16].
// ---------------------------------------------------------------------------
__global__ __launch_bounds__(256, 4)
void scorepv_kernel(const float* __restrict__ Eq, const float* __restrict__ Ek,
                    const float* __restrict__ values, const int* __restrict__ vlens,
                    const float* __restrict__ wv,
                    float* __restrict__ partial, float* __restrict__ tsum)
{
  const int blk = blockIdx.x;
  const int g   = blk >> 3;            // g = kt*16 + b
  const int qq  = blk & 7;             // low bits -> XCD id: balanced
  const int kt  = g >> 4;
  const int b   = g & 15;
  const int vl  = vlens[b];
  if (kt * 128 >= vl) return;

  __shared__ float ek_lds[64 * 128];   // [h][k] 32KB; reused as p_lds + red

  const int t = threadIdx.x;

  // stage Ek [128k][64h] -> ek_lds[h][k]  (transpose; conflict-free b64 writes)
  {
    const float4* src = (const float4*)(Ek + ((size_t)(b * 2048 + kt * 128)) * 64);
    #pragma unroll
    for (int i = 0; i < 4; ++i) {
      int u   = t + 256 * i;           // 0..1023
      int kp2 = u & 63;                // k-pair
      int hq  = u >> 6;                // h-quad 0..15
      float4 a0 = src[(2 * kp2) * 16 + hq];
      float4 a1 = src[(2 * kp2 + 1) * 16 + hq];
      *(float2*)&ek_lds[(4 * hq + 0) * 128 + 2 * kp2] = make_float2(a0.x, a1.x);
      *(float2*)&ek_lds[(4 * hq + 1) * 128 + 2 * kp2] = make_float2(a0.y, a1.y);
      *(float2*)&ek_lds[(4 * hq + 2) * 128 + 2 * kp2] = make_float2(a0.z, a1.z);
      *(float2*)&ek_lds[(4 * hq + 3) * 128 + 2 * kp2] = make_float2(a0.w, a1.w);
    }
  }

  // w0 = sum wv, W1 = sum |wv| (uniform -> scalar pipe)
  float w0 = 0.f, W1 = 0.f;
  #pragma unroll
  for (int u = 0; u < 16; ++u) {
    float4 v = ((const float4*)wv)[u];
    w0 += v.x + v.y + v.z + v.w;
    W1 += fabsf(v.x) + fabsf(v.y) + fabsf(v.z) + fabsf(v.w);
  }

  __syncthreads();

  const int wave_u = __builtin_amdgcn_readfirstlane(t >> 6);  // uniform wave id
  const int lane   = t & 63;
  const int q0g    = qq * 16 + wave_u * 4;   // wave's 4 exclusive q rows
  const int kp     = lane * 2;               // lane's k pair
  const float* eqb = Eq + (size_t)(b * 128 + q0g) * 64;

  float s[4][2];
  #pragma unroll
  for (int q = 0; q < 4; ++q) { s[q][0] = w0; s[q][1] = w0; }

  #pragma unroll 4
  for (int hp = 0; hp < 32; ++hp) {          // h-pairs
    float2 ekA = *(const float2*)&ek_lds[(2 * hp) * 128 + kp];     // h=2hp
    float2 ekB = *(const float2*)&ek_lds[(2 * hp + 1) * 128 + kp]; // h=2hp+1
    float2 wvp = *(const float2*)&wv[2 * hp];  // uniform -> SGPR
    float wa = -2.0f * wvp.x, wb = -2.0f * wvp.y;
    #pragma unroll
    for (int q = 0; q < 4; ++q) {
      float2 eqp = *(const float2*)&eqb[q * 64 + 2 * hp];  // uniform -> s_load
      {  // k = kp
        float x0 = fmaf(eqp.x, ekA.x, 1.f);
        float x1 = fmaf(eqp.y, ekB.x, 1.f);
        float y  = fast_rcp(x0 * x1);
        float a  = wb * x0;
        a = fmaf(wa, x1, a);
        s[q][0] = fmaf(a, y, s[q][0]);
      }
      {  // k = kp+1
        float x0 = fmaf(eqp.x, ekA.y, 1.f);
        float x1 = fmaf(eqp.y, ekB.y, 1.f);
        float y  = fast_rcp(x0 * x1);
        float a  = wb * x0;
        a = fmaf(wa, x1, a);
        s[q][1] = fmaf(a, y, s[q][1]);
      }
    }
  }

  // p = exp2((s - W1)*L2E) in (0,1]; masked -> 0 (select, garbage/NaN-safe)
  const int kbase = kt * 128 + kp;
  float p[4][2];
  #pragma unroll
  for (int q = 0; q < 4; ++q) {
    p[q][0] = (kbase     < vl) ? fast_exp2((s[q][0] - W1) * L2E) : 0.f;
    p[q][1] = (kbase + 1 < vl) ? fast_exp2((s[q][1] - W1) * L2E) : 0.f;
  }

  // per-tile row sums (wave owns its q rows exclusively)
  #pragma unroll
  for (int q = 0; q < 4; ++q) {
    float e = p[q][0] + p[q][1];
    #pragma unroll
    for (int m = 1; m < 64; m <<= 1) e += __shfl_xor(e, m, 64);
    if (lane == 0) tsum[(size_t)(b * 16 + kt) * 128 + q0g + q] = e;
  }

  __syncthreads();                     // all ek reads complete before reuse
  float* p_lds = ek_lds;               // [128 k][20 pad]
  const int q0l = wave_u * 4;
  *(float4*)&p_lds[kp * 20 + q0l]       = make_float4(p[0][0], p[1][0], p[2][0], p[3][0]);
  *(float4*)&p_lds[(kp + 1) * 20 + q0l] = make_float4(p[0][1], p[1][1], p[2][1], p[3][1]);
  __syncthreads();

  // PV: thread (kg 0..1, v); kg owns 64 k; p float4 wave-uniform broadcasts
  const int kg = t >> 7, v = t & 127;
  const int kloc = min(128, vl - kt * 128);
  const int k0 = kg * 64, k1 = min(k0 + 64, kloc);
  const float* vb = values + ((size_t)(b * 2048 + kt * 128)) * 128 + v;
  float acc[16];
  #pragma unroll
  for (int i = 0; i < 16; ++i) acc[i] = 0.f;

  #pragma unroll 4
  for (int k = k0; k < k1; ++k) {
    float vx = vb[(size_t)k * 128];
    const float* pr = &p_lds[k * 20];
    float4 p0 = *(const float4*)&pr[0];
    float4 p1 = *(const float4*)&pr[4];
    float4 p2 = *(const float4*)&pr[8];
    float4 p3 = *(const float4*)&pr[12];
    acc[ 0] = fmaf(p0.x, vx, acc[ 0]); acc[ 1] = fmaf(p0.y, vx, acc[ 1]);
    acc[ 2] = fmaf(p0.z, vx, acc[ 2]); acc[ 3] = fmaf(p0.w, vx, acc[ 3]);
    acc[ 4] = fmaf(p1.x, vx, acc[ 4]); acc[ 5] = fmaf(p1.y, vx, acc[ 5]);
    acc[ 6] = fmaf(p1.z, vx, acc[ 6]); acc[ 7] = fmaf(p1.w, vx, acc[ 7]);
    acc[ 8] = fmaf(p2.x, vx, acc[ 8]); acc[ 9] = fmaf(p2.y, vx, acc[ 9]);
    acc[10] = fmaf(p2.z, vx, acc[10]); acc[11] = fmaf(p2.w, vx, acc[11]);
    acc[12] = fmaf(p3.x, vx, acc[12]); acc[13] = fmaf(p3.y, vx, acc[13]);
    acc[14] = fmaf(p3.z, vx, acc[14]); acc[15] = fmaf(p3.w, vx, acc[15]);
  }

  // cross-kg reduction: red region does NOT alias p_lds (2560+2048 <= 8192)
  float* red = ek_lds + 128 * 20;      // [16 q][128 v]
  if (kg == 1) {
    #pragma unroll
    for (int q = 0; q < 16; ++q) red[q * 128 + v] = acc[q];
  }
  __syncthreads();
  if (kg == 0) {
    #pragma unroll
    for (int q = 0; q < 16; ++q) {
      float tot = acc[q] + red[q * 128 + v];
      partial[(((size_t)(b * 128 + qq * 16 + q)) * 16 + kt) * 128 + v] = tot;
    }
  }
}

// ---------------------------------------------------------------------------
// Reduce: out[b][q][v] = sum_kt partial / sum_kt tsum. Block = (b, 2-q), 256 thr.
// ---------------------------------------------------------------------------
__global__ __launch_bounds__(256)
void reduce_kernel(const float* __restrict__ partial, const float* __restrict__ tsum,
                   const int* __restrict__ vlens, float* __restrict__ out)
{
  const int blk = blockIdx.x;          // b*64 + qp
  const int b   = blk >> 6;
  const int q   = (blk & 63) * 2 + (threadIdx.x >> 7);
  const int v   = threadIdx.x & 127;
  const int ntk = (vlens[b] + 127) >> 7;

  float tot = 0.f;
  for (int i = 0; i < ntk; ++i)
    tot += tsum[(size_t)(b * 16 + i) * 128 + q];

  float acc = 0.f;
  const float* pp = partial + ((size_t)(b * 128 + q)) * 16 * 128 + v;
  for (int i = 0; i < ntk; ++i)
    acc += pp[(size_t)i * 128];

  out[((size_t)(b * 128 + q)) * 128 + v] = acc / tot;
}

// ---------------------------------------------------------------------------
// Fallback fused kernel (round-1, known-correct) for small ws_size.
// Uses the TRANSPOSED Ek layout.
// ---------------------------------------------------------------------------
__global__ __launch_bounds__(256)
void attn_kernel(const float* __restrict__ Eq, const float* __restrict__ EkT,
                 const float* __restrict__ values, const int* __restrict__ vlens,
                 const float* __restrict__ wv, float* __restrict__ out)
{
  const int t    = threadIdx.x;
  const int b    = blockIdx.x & 15;
  const int qt   = blockIdx.x >> 4;
  const int wave = t >> 6;
  const int lane = t & 63;

  __shared__ float4 sc4[512 * 4];
  __shared__ float  pvp[128 * 5];
  __shared__ float  linvs[4];

  const int vl = vlens[b];

  float eqv[64], wv2[64];
  float w0 = 0.f;
  {
    const float4* eq4 = (const float4*)(Eq + (size_t)(b * 128 + qt * 4 + wave) * 64);
    const float4* wv4 = (const float4*)wv;
    #pragma unroll
    for (int u = 0; u < 16; ++u) {
      float4 e = eq4[u], v = wv4[u];
      eqv[4*u+0] = e.x; eqv[4*u+1] = e.y; eqv[4*u+2] = e.z; eqv[4*u+3] = e.w;
      wv2[4*u+0] = -2.f * v.x; wv2[4*u+1] = -2.f * v.y;
      wv2[4*u+2] = -2.f * v.z; wv2[4*u+3] = -2.f * v.w;
      w0 += v.x + v.y + v.z + v.w;
    }
  }

  const int ktiles = (vl + 127) >> 7;
  const int kp = 2 * lane;
  for (int kt = 0; kt < ktiles; ++kt) {
    const float* tb = EkT + ((size_t)(b * 16 + kt) * 64) * 128 + kp;
    float s0 = w0, s1 = w0;
    #pragma unroll
    for (int h = 0; h < 64; ++h) {
      float2 ek = *(const float2*)(tb + (size_t)h * 128);
      float r0 = fast_rcp(fmaf(eqv[h], ek.x, 1.0f));
      float r1 = fast_rcp(fmaf(eqv[h], ek.y, 1.0f));
      s0 = fmaf(wv2[h], r0, s0);
      s1 = fmaf(wv2[h], r1, s1);
    }
    int k = kt * 128 + kp;
    if (k     >= vl) s0 = -1e9f;
    if (k + 1 >= vl) s1 = -1e9f;
    float* scf = (float*)sc4;
    *(float2*)(scf + (((k >> 2) * 4 + wave) * 4 + (k & 3))) = make_float2(s0, s1);
  }

  const int nq4 = (vl + 3) >> 2;
  float mx = -3e38f;
  for (int Q = lane; Q < nq4; Q += 64) {
    float4 f = sc4[Q * 4 + wave];
    mx = fmaxf(mx, fmaxf(fmaxf(f.x, f.y), fmaxf(f.z, f.w)));
  }
  #pragma unroll
  for (int msk = 1; msk < 64; msk <<= 1) mx = fmaxf(mx, __shfl_xor(mx, msk, 64));
  float lsum = 0.f;
  for (int Q = lane; Q < nq4; Q += 64) {
    float4 f = sc4[Q * 4 + wave];
    f.x = fast_exp2((f.x - mx) * L2E);
    f.y = fast_exp2((f.y - mx) * L2E);
    f.z = fast_exp2((f.z - mx) * L2E);
    f.w = fast_exp2((f.w - mx) * L2E);
    sc4[Q * 4 + wave] = f;
    lsum += f.x + f.y + f.z + f.w;
  }
  #pragma unroll
  for (int msk = 1; msk < 64; msk <<= 1) lsum += __shfl_xor(lsum, msk, 64);
  if (lane == 0) linvs[wave] = fast_rcp(lsum);
  __syncthreads();

  const int grp = t >> 7, v = t & 127;
  float acc[4] = {0.f, 0.f, 0.f, 0.f};
  const float* vb = values + (size_t)b * 2048 * 128 + v;
  for (int Q = grp; Q < nq4; Q += 2) {
    float4 p0 = sc4[Q * 4 + 0], p1 = sc4[Q * 4 + 1];
    float4 p2 = sc4[Q * 4 + 2], p3 = sc4[Q * 4 + 3];
    const float* vk = vb + (size_t)(Q * 4) * 128;
    float x;
    x = vk[0];
    acc[0]=fmaf(p0.x,x,acc[0]); acc[1]=fmaf(p1.x,x,acc[1]);
    acc[2]=fmaf(p2.x,x,acc[2]); acc[3]=fmaf(p3.x,x,acc[3]);
    x = vk[128];
    acc[0]=fmaf(p0.y,x,acc[0]); acc[1]=fmaf(p1.y,x,acc[1]);
    acc[2]=fmaf(p2.y,x,acc[2]); acc[3]=fmaf(p3.y,x,acc[3]);
    x = vk[256];
    acc[0]=fmaf(p0.z,x,acc[0]); acc[1]=fmaf(p1.z,x,acc[1]);
    acc[2]=fmaf(p2.z,x,acc[2]); acc[3]=fmaf(p3.z,x,acc[3]);
    x = vk[384];
    acc[0]=fmaf(p0.w,x,acc[0]); acc[1]=fmaf(p1.w,x,acc[1]);
    acc[2]=fmaf(p2.w,x,acc[2]); acc[3]=fmaf(p3.w,x,acc[3]);
  }
  if (grp == 1) {
    #pragma unroll
    for (int qq = 0; qq < 4; ++qq) pvp[v * 5 + qq] = acc[qq];
  }
  __syncthreads();
  if (grp == 0) {
    #pragma unroll
    for (int qq = 0; qq < 4; ++qq) {
      float tot = acc[qq] + pvp[v * 5 + qq];
      out[((size_t)(b * 128) + qt * 4 + qq) * 128 + v] = tot * linvs[qq];
    }
  }
}

// ---------------------------------------------------------------------------
extern "C" void kernel_launch(void* const* d_in, const int* in_sizes, int n_in,
                              void* d_out, int out_size, void* d_ws, size_t ws_size,
                              hipStream_t stream) {
  const float* queries = (const float*)d_in[0];   // [16][128][256]
  const float* keys    = (const float*)d_in[1];   // [16][2048][256]
  const float* values  = (const float*)d_in[2];   // [16][2048][128]
  const int*   vlens   = (const int*)d_in[3];     // [16]
  const float* Wq      = (const float*)d_in[4];   // [256][64]
  const float* Wk      = (const float*)d_in[5];   // [256][64]
  const float* wv      = (const float*)d_in[6];   // [64]
  float* outp = (float*)d_out;

  float* base    = (float*)d_ws;
  float* Eq      = base;                 // 131072 f
  float* Ek      = base + 131072;        // 2097152 f  (row-major [b][k][h])
  float* tsumb   = base + 2228224;       // 32768 f    [b][kt][q]
  float* partial = base + 2260992;       // 4194304 f  [b][q][kt][v]
  const size_t need = (size_t)(2260992 + 4194304) * 4;

  if (ws_size >= need) {
    hipLaunchKernelGGL(proj_qk_kernel, dim3(544), dim3(256), 0, stream,
                       queries, keys, Wq, Wk, Eq, Ek, vlens);
    hipLaunchKernelGGL(scorepv_kernel, dim3(2048), dim3(256), 0, stream,
                       Eq, Ek, values, vlens, wv, partial, tsumb);
    hipLaunchKernelGGL(reduce_kernel, dim3(1024), dim3(256), 0, stream,
                       partial, tsumb, vlens, outp);
  } else {
    hipLaunchKernelGGL((proj_kernel<false, false>), dim3(32), dim3(256), 0, stream,
                       queries, Wq, Eq, (const int*)nullptr, 128);
    hipLaunchKernelGGL((proj_kernel<true, true>), dim3(512), dim3(256), 0, stream,
                       keys, Wk, Ek, vlens, 2048);
    hipLaunchKernelGGL(attn_kernel, dim3(512), dim3(256), 0, stream,
                       Eq, Ek, values, vlens, wv, outp);
  }
}